// Round 1
// baseline (187.639 us; speedup 1.0000x reference)
//
#include <hip/hip_runtime.h>
#include <hip/hip_bf16.h>

#define ROWS 64
#define CELLS 64
#define CN_LEN 8
#define CV_LEN 16
#define EMB 768
#define HID 3072
#define NCELL 4096
#define L_CV 1024
#define ROW_TOK 1089  /* 1 cls + 64 cn + 1024 cv */

// ---- workspace layout (bytes) ----
#define OFF_ACC   0UL
#define OFF_FGATE 32UL
#define OFF_GPRE  64UL
#define ZERO_BYTES (64UL + 4096UL*4)            /* acc8 + fgate + g_pre */
#define OFF_CNF   16448UL                        /* 4096x768 f32 */
#define OFF_CNB   (OFF_CNF + 4096UL*768*4)       /* 4096x768 bf16 */
#define OFF_W1T   (OFF_CNB + 4096UL*768*2)       /* 3072x768 bf16 (transposed gate_w1) */
#define OFF_IDX   (OFF_W1T + 3072UL*768*2)       /* 64x1024 int */
#define OFF_CNT   (OFF_IDX + 65536UL*4)          /* 64 int */

typedef __attribute__((ext_vector_type(8))) short bf16x8;
typedef __attribute__((ext_vector_type(4))) float f32x4;

static __device__ __forceinline__ short f2bf(float x) {
  unsigned u = __float_as_uint(x);
  unsigned r = (u + 0x7fffu + ((u >> 16) & 1u)) >> 16;
  return (short)r;
}

// ---------- fgate: per-type fuse-MLP scalar (8 types only) ----------
__global__ __launch_bounds__(256) void k_fgate_acc(
    const float* __restrict__ type_emb, const float* __restrict__ fuse_w1,
    const float* __restrict__ fuse_b1, const float* __restrict__ fuse_w2,
    float* __restrict__ acc8) {
  __shared__ float te[8 * EMB];
  const int tid = threadIdx.x;
  for (int i = tid; i < 8 * EMB; i += 256) te[i] = type_emb[i];
  __syncthreads();
  const int t = tid >> 5, hl = tid & 31;
  const int h = blockIdx.x * 32 + hl;
  float a = fuse_b1[h];
  const float* w1c = fuse_w1 + h;
  const float* tr = te + t * EMB;
  for (int e = 0; e < EMB; e++) a += tr[e] * w1c[(size_t)e * HID];
  float v = fmaxf(a, 0.f) * fuse_w2[h];
  #pragma unroll
  for (int m = 1; m < 32; m <<= 1) v += __shfl_xor(v, m);
  if (hl == 0) atomicAdd(&acc8[t], v);
}

__global__ void k_fgate_fin(const float* __restrict__ acc8,
                            const float* __restrict__ fuse_b2,
                            float* __restrict__ fgate) {
  const int t = threadIdx.x;
  if (t < 8) fgate[t] = 1.f / (1.f + expf(-(acc8[t] + fuse_b2[0])));
}

// ---------- transpose + bf16-convert gate_w1 [768xH] -> w1t [Hx768] ----------
__global__ __launch_bounds__(256) void k_w1t(const float* __restrict__ w1,
                                             short* __restrict__ w1t) {
  __shared__ float tile[32][33];
  const int bx = blockIdx.x, by = blockIdx.y;  // bx: h tile, by: e tile
  const int tid = threadIdx.x;
  #pragma unroll
  for (int i = 0; i < 4; i++) {
    int idx = tid + i * 256;
    int rr = idx >> 5, cc = idx & 31;
    tile[rr][cc] = w1[(size_t)(by * 32 + rr) * HID + bx * 32 + cc];
  }
  __syncthreads();
  #pragma unroll
  for (int i = 0; i < 4; i++) {
    int idx = tid + i * 256;
    int rr = idx >> 5, cc = idx & 31;
    w1t[(size_t)(bx * 32 + rr) * EMB + by * 32 + cc] = f2bf(tile[cc][rr]);
  }
}

// ---------- cn_e: masked avg + type gate; write out cn region + cls ----------
__global__ __launch_bounds__(192) void k_cn(
    const int* __restrict__ cn_ids, const int* __restrict__ cn_mask,
    const int* __restrict__ c_types, const float* __restrict__ word_emb,
    const float* __restrict__ type_emb, const float* __restrict__ cls_w,
    const float* __restrict__ fgate, float* __restrict__ cnf,
    short* __restrict__ cnb, float* __restrict__ out) {
  const int n = blockIdx.x, tid = threadIdx.x;
  const int row = n >> 6, cell = n & 63;
  const int* ids = cn_ids + n * CN_LEN;
  const int* msk = cn_mask + n * CN_LEN;
  float4 s = {0.f, 0.f, 0.f, 0.f};
  int cnt = 0;
  #pragma unroll
  for (int j = 0; j < CN_LEN; j++) {
    if (msk[j]) {
      cnt++;
      const float4 v = *(const float4*)&word_emb[(size_t)ids[j] * EMB + tid * 4];
      s.x += v.x; s.y += v.y; s.z += v.z; s.w += v.w;
    }
  }
  const float inv = 1.f / (float)cnt;
  const int t = c_types[n];
  const float fg = fgate[t];
  const float4 d = *(const float4*)&type_emb[(size_t)t * EMB + tid * 4];
  float4 c;
  c.x = s.x * inv + d.x * fg;
  c.y = s.y * inv + d.y * fg;
  c.z = s.z * inv + d.z * fg;
  c.w = s.w * inv + d.w * fg;
  *(float4*)&cnf[(size_t)n * EMB + tid * 4] = c;
  short4 b;
  b.x = f2bf(c.x); b.y = f2bf(c.y); b.z = f2bf(c.z); b.w = f2bf(c.w);
  *(short4*)&cnb[(size_t)n * EMB + tid * 4] = b;
  *(float4*)&out[(size_t)row * ROW_TOK * EMB + (size_t)(1 + cell) * EMB + tid * 4] = c;
  if (cell == 0)
    *(float4*)&out[(size_t)row * ROW_TOK * EMB + tid * 4] =
        *(const float4*)&cls_w[tid * 4];
}

// ---------- gate MLP: bf16 MFMA GEMM with fused relu*w2 row-reduce ----------
__global__ __launch_bounds__(256) void k_gate_gemm(
    const short* __restrict__ cnb, const short* __restrict__ w1t,
    const float* __restrict__ gate_b1, const float* __restrict__ gate_w2,
    float* __restrict__ g_pre) {
  __shared__ short Asub[64][40];
  __shared__ short Bsub[256][40];
  const int tid = threadIdx.x;
  const int n0 = blockIdx.x * 64;
  const int h0 = blockIdx.y * 256;
  const int lane = tid & 63, w = tid >> 6;
  const int r = lane & 15, g = lane >> 4;
  f32x4 acc[4][4];
  #pragma unroll
  for (int a = 0; a < 4; a++)
    #pragma unroll
    for (int b = 0; b < 4; b++) acc[a][b] = (f32x4)0.f;
  const int arow = tid >> 2, ak = (tid & 3) * 8;

  for (int kk = 0; kk < EMB; kk += 32) {
    *(uint4*)&Asub[arow][ak] = *(const uint4*)&cnb[(size_t)(n0 + arow) * EMB + kk + ak];
    const short* bsrc = &w1t[(size_t)(h0 + tid) * EMB + kk];
    *(uint4*)&Bsub[tid][0]  = *(const uint4*)&bsrc[0];
    *(uint4*)&Bsub[tid][8]  = *(const uint4*)&bsrc[8];
    *(uint4*)&Bsub[tid][16] = *(const uint4*)&bsrc[16];
    *(uint4*)&Bsub[tid][24] = *(const uint4*)&bsrc[24];
    __syncthreads();
    bf16x8 fa[4], fb[4];
    #pragma unroll
    for (int fm = 0; fm < 4; fm++) {
      const short* ap = &Asub[fm * 16 + r][0];
      short4 lo = *(const short4*)(ap + 4 * g);
      short4 hi = *(const short4*)(ap + 16 + 4 * g);
      fa[fm] = (bf16x8){lo.x, lo.y, lo.z, lo.w, hi.x, hi.y, hi.z, hi.w};
    }
    #pragma unroll
    for (int fn = 0; fn < 4; fn++) {
      const short* bp = &Bsub[w * 64 + fn * 16 + r][0];
      short4 lo = *(const short4*)(bp + 4 * g);
      short4 hi = *(const short4*)(bp + 16 + 4 * g);
      fb[fn] = (bf16x8){lo.x, lo.y, lo.z, lo.w, hi.x, hi.y, hi.z, hi.w};
    }
    #pragma unroll
    for (int fm = 0; fm < 4; fm++)
      #pragma unroll
      for (int fn = 0; fn < 4; fn++)
        acc[fm][fn] = __builtin_amdgcn_mfma_f32_16x16x32_bf16(
            fa[fm], fb[fn], acc[fm][fn], 0, 0, 0);
    __syncthreads();
  }

  // epilogue: rowsum over this block's 256 h of relu(v + b1[h]) * w2[h]
  #pragma unroll
  for (int fm = 0; fm < 4; fm++) {
    float rs[4] = {0.f, 0.f, 0.f, 0.f};
    #pragma unroll
    for (int fn = 0; fn < 4; fn++) {
      const int h = h0 + w * 64 + fn * 16 + r;
      const float bv = gate_b1[h];
      const float wv = gate_w2[h];
      #pragma unroll
      for (int q = 0; q < 4; q++) {
        float v = acc[fm][fn][q] + bv;
        v = v > 0.f ? v : 0.f;
        rs[q] += v * wv;
      }
    }
    #pragma unroll
    for (int q = 0; q < 4; q++)
      #pragma unroll
      for (int m = 1; m < 16; m <<= 1) rs[q] += __shfl_xor(rs[q], m);
    if (r == 0) {
      #pragma unroll
      for (int q = 0; q < 4; q++)
        atomicAdd(&g_pre[n0 + fm * 16 + g * 4 + q], rs[q]);
    }
  }
}

// ---------- per-row prefix sum over cv_mask -> compact index list ----------
__global__ __launch_bounds__(256) void k_prefix(const int* __restrict__ cv_mask,
                                                int* __restrict__ idxl,
                                                int* __restrict__ cnt) {
  const int row = blockIdx.x, tid = threadIdx.x;
  __shared__ int ssum[256];
  int m[4];
  const int base = row * L_CV + tid * 4;
  int s = 0;
  #pragma unroll
  for (int i = 0; i < 4; i++) { m[i] = cv_mask[base + i]; s += m[i]; }
  ssum[tid] = s;
  __syncthreads();
  for (int off = 1; off < 256; off <<= 1) {
    int v = (tid >= off) ? ssum[tid - off] : 0;
    __syncthreads();
    ssum[tid] += v;
    __syncthreads();
  }
  int p = ssum[tid] - s;  // exclusive prefix
  #pragma unroll
  for (int i = 0; i < 4; i++)
    if (m[i]) { idxl[row * L_CV + p] = tid * 4 + i; p++; }
  if (tid == 255) cnt[row] = ssum[255];
}

// ---------- cv region: one block per output slot (compact or zero) ----------
__global__ __launch_bounds__(192) void k_cv(
    const int* __restrict__ cv_ids, const int* __restrict__ idxl,
    const int* __restrict__ cnt, const float* __restrict__ word_emb,
    const float* __restrict__ cnf, const float* __restrict__ g_pre,
    const float* __restrict__ gate_b2, float* __restrict__ out) {
  const int k = blockIdx.x, row = blockIdx.y, tid = threadIdx.x;
  const size_t obase = (size_t)row * ROW_TOK * EMB + (size_t)(65 + k) * EMB;
  float4 v = {0.f, 0.f, 0.f, 0.f};
  if (k < cnt[row]) {
    const int j = idxl[row * L_CV + k];
    const int n = row * CELLS + (j >> 4);
    const int tok = j & 15;
    const int id = cv_ids[n * CV_LEN + tok];
    const float gg = 1.f / (1.f + expf(-(g_pre[n] + gate_b2[0])));
    const float4 we = *(const float4*)&word_emb[(size_t)id * EMB + tid * 4];
    const float4 cn = *(const float4*)&cnf[(size_t)n * EMB + tid * 4];
    v.x = we.x + cn.x * gg;
    v.y = we.y + cn.y * gg;
    v.z = we.z + cn.z * gg;
    v.w = we.w + cn.w * gg;
  }
  *(float4*)&out[obase + tid * 4] = v;
}

extern "C" void kernel_launch(void* const* d_in, const int* in_sizes, int n_in,
                              void* d_out, int out_size, void* d_ws, size_t ws_size,
                              hipStream_t stream) {
  const int* cn_ids    = (const int*)d_in[0];
  const int* cn_mask   = (const int*)d_in[1];
  const int* c_types   = (const int*)d_in[2];
  const int* cv_ids    = (const int*)d_in[3];
  const int* cv_mask   = (const int*)d_in[4];
  const float* word_emb = (const float*)d_in[5];
  const float* type_emb = (const float*)d_in[6];
  const float* fuse_w1  = (const float*)d_in[7];
  const float* fuse_b1  = (const float*)d_in[8];
  const float* fuse_w2  = (const float*)d_in[9];
  const float* fuse_b2  = (const float*)d_in[10];
  const float* gate_w1  = (const float*)d_in[11];
  const float* gate_b1  = (const float*)d_in[12];
  const float* gate_w2  = (const float*)d_in[13];
  const float* gate_b2  = (const float*)d_in[14];
  const float* cls_w    = (const float*)d_in[15];

  char* ws = (char*)d_ws;
  float* acc8  = (float*)(ws + OFF_ACC);
  float* fgate = (float*)(ws + OFF_FGATE);
  float* gpre  = (float*)(ws + OFF_GPRE);
  float* cnf   = (float*)(ws + OFF_CNF);
  short* cnb   = (short*)(ws + OFF_CNB);
  short* w1t   = (short*)(ws + OFF_W1T);
  int*   idxl  = (int*)(ws + OFF_IDX);
  int*   cntp  = (int*)(ws + OFF_CNT);
  float* out   = (float*)d_out;

  hipMemsetAsync(ws, 0, ZERO_BYTES, stream);
  k_fgate_acc<<<96, 256, 0, stream>>>(type_emb, fuse_w1, fuse_b1, fuse_w2, acc8);
  k_fgate_fin<<<1, 64, 0, stream>>>(acc8, fuse_b2, fgate);
  k_w1t<<<dim3(96, 24), 256, 0, stream>>>(gate_w1, w1t);
  k_cn<<<NCELL, 192, 0, stream>>>(cn_ids, cn_mask, c_types, word_emb, type_emb,
                                  cls_w, fgate, cnf, cnb, out);
  k_gate_gemm<<<dim3(64, 12), 256, 0, stream>>>(cnb, w1t, gate_b1, gate_w2, gpre);
  k_prefix<<<64, 256, 0, stream>>>(cv_mask, idxl, cntp);
  k_cv<<<dim3(L_CV, ROWS), 192, 0, stream>>>(cv_ids, idxl, cntp, word_emb, cnf,
                                             gpre, gate_b2, out);
}